// Round 6
// baseline (315.506 us; speedup 1.0000x reference)
//
#include <hip/hip_runtime.h>
#include <hip/hip_cooperative_groups.h>
#include <math.h>

namespace cg = cooperative_groups;

#define N_INP 128
#define N_HID 512
#define N_OUT 256
#define N_HEADS 64
#define N_SM 4
#define EPS_GN 1e-5f
#define TINY 1e-14f

// ---- DPP tree reductions: pure VALU (no LDS pipe) ----
// row_shr:k = 0x110|k ; row_bcast:15 = 0x142 ; row_bcast:31 = 0x143
template <int CTRL>
__device__ __forceinline__ float dpp_add(float v) {
  int x = __builtin_amdgcn_update_dpp(0, __float_as_int(v), CTRL, 0xF, 0xF, true);
  return v + __int_as_float(x);
}
// sum of each 16-lane group -> lane (gl==15) of the group
__device__ __forceinline__ float red16(float v) {
  v = dpp_add<0x111>(v);
  v = dpp_add<0x112>(v);
  v = dpp_add<0x114>(v);
  v = dpp_add<0x118>(v);
  return v;
}
// sum of each 32-lane group -> lane (q==31) of the group
__device__ __forceinline__ float red32(float v) {
  v = red16(v);
  v = dpp_add<0x142>(v);
  return v;
}
// sum of the whole wave -> lane 63
__device__ __forceinline__ float red64(float v) {
  v = red32(v);
  v = dpp_add<0x143>(v);
  return v;
}

// Block reduction: ALL threads must call; `red` needs blockDim/64 slots.
__device__ __forceinline__ float block_sum(float v, float* red) {
  int wave = threadIdx.x >> 6, lane = threadIdx.x & 63;
  int nw = blockDim.x >> 6;
  v = red64(v);
  __syncthreads();
  if (lane == 63) red[wave] = v;
  __syncthreads();
  float s = 0.f;
  for (int i = 0; i < nw; ++i) s += red[i];
  return s;
}

// Single cooperative kernel: 256 blocks (= 1/CU, co-resident) x 1024 threads.
// Phase A: z1 quarter (old K1) with w2 round-0 prefetch in flight across it.
// grid.sync()  (the ONLY coherence points — no per-block fences mid-stream)
// Phase B: GN1+softplus, 512KB w2 stream (double-buffered, DPP red32),
//          GN2+softmax -> part, fused wsc slice (old K2).
// grid.sync()
// Phase C: blocks 0..63 do the gate + final outputs (old K3).
__global__ __launch_bounds__(1024) void k_fused(
    const float* __restrict__ x, const float* __restrict__ last,
    const float* __restrict__ qw, const float* __restrict__ w1,
    const float* __restrict__ g1, const float* __restrict__ b1,
    const float* __restrict__ w2, const float* __restrict__ g2,
    const float* __restrict__ b2, const float* __restrict__ wsc,
    const float* __restrict__ woo, float* __restrict__ z1,
    float* __restrict__ zstat, float* __restrict__ part,
    float* __restrict__ scal, float* __restrict__ out) {
  cg::grid_group grid = cg::this_grid();
  int blk = blockIdx.x;            // s*64 + h
  int s = blk >> 6, h = blk & 63;
  int tid = threadIdx.x, wave = tid >> 6, lane = tid & 63;
  int g32 = lane >> 5, q = lane & 31;    // half-wave group, lane-in-group
  int g = lane >> 4, gl = lane & 15;     // 16-lane group view
  int grp = wave * 4 + g;                // 0..63 (16-lane group id)

  __shared__ float sub_s[N_INP];
  __shared__ float h1_s[N_HID];
  __shared__ float z_s[N_OUT];
  __shared__ float2 red2[64];
  __shared__ float red[16];

  const float* w2base = w2 + (size_t)blk * N_OUT * N_HID;
  int row0 = wave * 16 + g32 * 8;  // this group's first w2 row

  // prefetch w2 round 0: 4 float4/lane — in flight across all of phase A
  float4 A[4], B[4];
  {
    const float4* rp = (const float4*)(w2base + (size_t)row0 * N_HID) + q;
#pragma unroll
    for (int c = 0; c < 4; ++c) A[c] = rp[c * 32];
  }

  // ---- phase A: sub = x·qw[h], then z1 quarter oq=s + (sum,sumsq) ----
  const float4* qrow = (const float4*)(qw + (size_t)h * N_INP);
  float4 Q0 = qrow[gl], Q1 = qrow[16 + gl];
#pragma unroll
  for (int j = 0; j < 2; ++j) {
    int r = grp + 64 * j;
    const float4* xr = (const float4*)(x + (size_t)r * N_INP);
    float4 X0 = xr[gl], X1 = xr[16 + gl];
    float p = X0.x * Q0.x + X0.y * Q0.y + X0.z * Q0.z + X0.w * Q0.w +
              X1.x * Q1.x + X1.y * Q1.y + X1.z * Q1.z + X1.w * Q1.w;
    p = red16(p);
    if (gl == 15) sub_s[r] = p;
  }
  __syncthreads();

  {
    const float4* sv = (const float4*)sub_s;
    float4 S0 = sv[gl], S1 = sv[16 + gl];
    const float* w1h = w1 + ((size_t)h * N_HID + (size_t)s * 128) * N_INP;
    float zs = 0.f, zq = 0.f;
#pragma unroll
    for (int j = 0; j < 2; ++j) {
      int o = grp + 64 * j;
      const float4* wr = (const float4*)(w1h + (size_t)o * N_INP);
      float4 W0 = wr[gl], W1 = wr[16 + gl];
      float p = W0.x * S0.x + W0.y * S0.y + W0.z * S0.z + W0.w * S0.w +
                W1.x * S1.x + W1.y * S1.y + W1.z * S1.z + W1.w * S1.w;
      p = red16(p);
      if (gl == 15) { z1[h * N_HID + s * 128 + o] = p; zs += p; zq += p * p; }
    }
    if (gl == 15) red2[grp] = make_float2(zs, zq);
  }
  __syncthreads();
  if (tid == 0) {
    float a = 0.f, b = 0.f;
#pragma unroll
    for (int i = 0; i < 64; ++i) { a += red2[i].x; b += red2[i].y; }
    zstat[(h * 4 + s) * 2] = a;
    zstat[(h * 4 + s) * 2 + 1] = b;
  }

  grid.sync();

  // ---- phase B: GN1 + softplus -> h1_s (stats from zstat, no reduction) ----
  float zsum = 0.f, zsq = 0.f;
#pragma unroll
  for (int qq = 0; qq < 4; ++qq) {
    zsum += zstat[(h * 4 + qq) * 2];
    zsq  += zstat[(h * 4 + qq) * 2 + 1];
  }
  float mu1 = zsum * (1.f / N_HID);
  float var1 = zsq * (1.f / N_HID) - mu1 * mu1;
  float r1 = rsqrtf(var1 + EPS_GN);
  if (tid < N_HID) {
    float v1 = z1[h * N_HID + tid];
    float zz = (v1 - mu1) * r1 * g1[h * N_HID + tid] + b1[h * N_HID + tid];
    h1_s[tid] = fmaxf(zz, 0.f) + log1pf(expf(-fabsf(zz)));
  }
  __syncthreads();

  // per-lane h1 fragment: floats q*4 + c*128 ..+3 (o-invariant)
  float4 H[4];
#pragma unroll
  for (int c = 0; c < 4; ++c) H[c] = ((const float4*)h1_s)[q + c * 32];

  // main loop: 8 rounds, double-buffered in registers; GN2 stats in-loop
  float as = 0.f, aq = 0.f;
#pragma unroll
  for (int r = 0; r < 8; ++r) {
    if (r < 7) {
      const float4* rp =
          (const float4*)(w2base + (size_t)(row0 + r + 1) * N_HID) + q;
#pragma unroll
      for (int c = 0; c < 4; ++c) B[c] = rp[c * 32];
    }
    float p = 0.f;
#pragma unroll
    for (int c = 0; c < 4; ++c)
      p += A[c].x * H[c].x + A[c].y * H[c].y + A[c].z * H[c].z + A[c].w * H[c].w;
    p = red32(p);
    if (q == 31) {
      z_s[row0 + r] = p;
      as += p; aq += p * p;
    }
#pragma unroll
    for (int c = 0; c < 4; ++c) A[c] = B[c];
  }
  if (q == 31) red2[wave * 2 + g32] = make_float2(as, aq);

  // fused wsc slice: 64 rows o in [s*64,(s+1)*64), one per 16-lane group
  {
    int o = s * 64 + wave * 4 + g;
    const float4* wr = (const float4*)(wsc + ((size_t)h * N_OUT + o) * N_OUT) + gl;
    float4 v0 = wr[0], v1 = wr[16], v2 = wr[32], v3 = wr[48];
    float p = v0.x + v0.y + v0.z + v0.w + v1.x + v1.y + v1.z + v1.w +
              v2.x + v2.y + v2.z + v2.w + v3.x + v3.y + v3.z + v3.w;
    p = red16(p);
    if (gl == 15) scal[o * N_HEADS + h] = p;
  }
  __syncthreads();

  // GN2 over 256 from the 32 group-partials; softmax (no max-subtract:
  // zn is GN-standardized, |zn| <= 16 — f32-safe)
  float sx = 0.f, sy = 0.f;
#pragma unroll
  for (int i = 0; i < 32; ++i) { sx += red2[i].x; sy += red2[i].y; }
  float mu = sx * (1.f / N_OUT);
  float var = sy * (1.f / N_OUT) - mu * mu;
  float rs = rsqrtf(var + EPS_GN);
  float e = (tid < N_OUT)
                ? expf((z_s[tid] - mu) * rs * g2[(size_t)blk * N_OUT + tid] +
                       b2[(size_t)blk * N_OUT + tid])
                : 0.f;
  float es = block_sum(e, red);
  if (tid < N_OUT) part[(size_t)blk * N_OUT + tid] = e / es;

  grid.sync();

  // ---- phase C: blocks 0..63 = one per head; gate + final outputs ----
  if (blk < N_HEADS) {
    int hh = blk;
    float osum = 0.f, gpart = 0.f;
    if (tid < N_OUT) {
#pragma unroll
      for (int ss = 0; ss < 4; ++ss)
        osum += part[(size_t)(ss * 64 + hh) * N_OUT + tid];
      // lp[o=tid] = prod_h last[o][h]
      const float4* rowL = (const float4*)(last + (size_t)tid * N_HEADS);
      float lp = 1.f;
#pragma unroll
      for (int j = 0; j < 16; ++j) {
        float4 v = rowL[j];
        lp *= v.x * v.y * v.z * v.w;
      }
      gpart = woo[hh * 2 * N_OUT + tid] * lp +
              woo[hh * 2 * N_OUT + N_OUT + tid] * osum;
    }
    float logit = block_sum(gpart, red);
    float oo = 1.f / (1.f + expf(-logit));
    if (tid < N_OUT) {
      float v0 = oo * osum;
      out[tid * N_HEADS + hh] = fmaxf(v0, TINY);
      float v1 = v0 * scal[tid * N_HEADS + hh];
      out[N_OUT * N_HEADS + tid * N_HEADS + hh] = (fabsf(v1) <= TINY) ? TINY : v1;
    }
  }
}

extern "C" void kernel_launch(void* const* d_in, const int* in_sizes, int n_in,
                              void* d_out, int out_size, void* d_ws, size_t ws_size,
                              hipStream_t stream) {
  const float* x    = (const float*)d_in[0];
  const float* last = (const float*)d_in[1];
  const float* qw   = (const float*)d_in[2];
  const float* w1   = (const float*)d_in[3];
  const float* g1   = (const float*)d_in[4];
  const float* b1   = (const float*)d_in[5];
  const float* w2   = (const float*)d_in[6];
  const float* g2   = (const float*)d_in[7];
  const float* b2   = (const float*)d_in[8];
  const float* wsc  = (const float*)d_in[9];
  const float* woo  = (const float*)d_in[10];
  float* out = (float*)d_out;
  float* ws  = (float*)d_ws;

  float* z1    = ws;               // 64*512          = 32768 floats
  float* zstat = ws + 32768;       // 256*2           = 512
  float* part  = ws + 33280;       // 4*64*256        = 65536
  float* scal  = ws + 98816;       // 256*64          = 16384

  void* args[] = {(void*)&x,   (void*)&last, (void*)&qw,  (void*)&w1,
                  (void*)&g1,  (void*)&b1,   (void*)&w2,  (void*)&g2,
                  (void*)&b2,  (void*)&wsc,  (void*)&woo, (void*)&z1,
                  (void*)&zstat, (void*)&part, (void*)&scal, (void*)&out};
  hipLaunchCooperativeKernel((const void*)k_fused, dim3(256), dim3(1024),
                             args, 0, stream);
}

// Round 8
// 241.978 us; speedup vs baseline: 1.3039x; 1.3039x over previous
//
#include <hip/hip_runtime.h>
#include <math.h>

#define N_INP 128
#define N_HID 512
#define N_OUT 256
#define N_HEADS 64
#define N_SM 4
#define EPS_GN 1e-5f
#define TINY 1e-14f

// ---- DPP tree reductions: pure VALU (no LDS pipe), ~4-8 cy per step ----
// row_shr:k = 0x110|k ; row_bcast:15 = 0x142 ; row_bcast:31 = 0x143
template <int CTRL>
__device__ __forceinline__ float dpp_add(float v) {
  int x = __builtin_amdgcn_update_dpp(0, __float_as_int(v), CTRL, 0xF, 0xF, true);
  return v + __int_as_float(x);
}
// sum of each 16-lane group -> lane (gl==15) of the group
__device__ __forceinline__ float red16(float v) {
  v = dpp_add<0x111>(v);
  v = dpp_add<0x112>(v);
  v = dpp_add<0x114>(v);
  v = dpp_add<0x118>(v);
  return v;
}
// sum of each 32-lane group -> lane (q==31) of the group
__device__ __forceinline__ float red32(float v) {
  v = red16(v);
  v = dpp_add<0x142>(v);  // row_bcast:15 -> lanes 16..31 (+48..63)
  return v;
}
// sum of the whole wave -> lane 63
__device__ __forceinline__ float red64(float v) {
  v = red32(v);
  v = dpp_add<0x143>(v);  // row_bcast:31 -> lanes 32..63
  return v;
}

// Block reduction: ALL threads must call; `red` needs blockDim/64 slots.
__device__ __forceinline__ float block_sum(float v, float* red) {
  int wave = threadIdx.x >> 6, lane = threadIdx.x & 63;
  int nw = blockDim.x >> 6;
  v = red64(v);
  __syncthreads();
  if (lane == 63) red[wave] = v;
  __syncthreads();
  float s = 0.f;
  for (int i = 0; i < nw; ++i) s += red[i];
  return s;
}

// K1: 256 blocks = (head h, quarter oq), 512 threads = 32 groups of 16.
// DPP-16 reductions (result lane gl==15). Emits z1 rows + per-quarter
// (sum,sumsq) so K2's GN1 needs no block reduction.
__global__ __launch_bounds__(512) void k_z1(
    const float* __restrict__ x, const float* __restrict__ qw,
    const float* __restrict__ w1, float* __restrict__ z1,
    float* __restrict__ zstat) {
  int blk = blockIdx.x;            // h*4 + oq
  int h = blk >> 2, oq = blk & 3;
  int tid = threadIdx.x, lane = tid & 63;
  int g = lane >> 4, gl = lane & 15;
  int grp = (tid >> 6) * 4 + g;    // 0..31
  __shared__ float sub_s[N_INP];
  __shared__ float2 wred[32];

  // per-lane q fragment: floats gl*4..+3 and 64+gl*4..+3
  const float4* qrow = (const float4*)(qw + (size_t)h * N_INP);
  float4 Q0 = qrow[gl], Q1 = qrow[16 + gl];

  // phase 1: sub[r] = x[r]·qw[h]; rows r = grp + 32j
#pragma unroll
  for (int j = 0; j < 4; ++j) {
    int r = grp + 32 * j;
    const float4* xr = (const float4*)(x + (size_t)r * N_INP);
    float4 X0 = xr[gl], X1 = xr[16 + gl];
    float p = X0.x * Q0.x + X0.y * Q0.y + X0.z * Q0.z + X0.w * Q0.w +
              X1.x * Q1.x + X1.y * Q1.y + X1.z * Q1.z + X1.w * Q1.w;
    p = red16(p);
    if (gl == 15) sub_s[r] = p;
  }
  __syncthreads();

  // phase 2: z1 rows o (within quarter oq) = grp + 32j; stats on gl==15
  const float4* sv = (const float4*)sub_s;
  float4 S0 = sv[gl], S1 = sv[16 + gl];
  const float* w1h = w1 + ((size_t)h * N_HID + (size_t)oq * 128) * N_INP;
  float zs = 0.f, zq = 0.f;
#pragma unroll
  for (int j = 0; j < 4; ++j) {
    int o = grp + 32 * j;
    const float4* wr = (const float4*)(w1h + (size_t)o * N_INP);
    float4 W0 = wr[gl], W1 = wr[16 + gl];
    float p = W0.x * S0.x + W0.y * S0.y + W0.z * S0.z + W0.w * S0.w +
              W1.x * S1.x + W1.y * S1.y + W1.z * S1.z + W1.w * S1.w;
    p = red16(p);
    if (gl == 15) { z1[h * N_HID + oq * 128 + o] = p; zs += p; zq += p * p; }
  }
  if (gl == 15) wred[grp] = make_float2(zs, zq);
  __syncthreads();
  if (tid == 0) {
    float a = 0.f, b = 0.f;
#pragma unroll
    for (int i = 0; i < 32; ++i) { a += wred[i].x; b += wred[i].y; }
    zstat[blk * 2] = a;
    zstat[blk * 2 + 1] = b;
  }
}

// K2: 256 blocks = one per (s,h), 1024 threads = 16 waves = 32 half-wave
// groups. Each 32-lane group owns 8 w2 rows (lane holds 16 floats = 4xfloat4
// of a row); DPP red32 per row (5 VALU steps, result q==31). A[4]+B[4]+H[4]
// = 48 array VGPRs -> no spill at the 128-VGPR cap, double-buffer stays in
// registers. GN1 from K1's stats (zero barriers); GN2 stats in-loop.
__global__ __launch_bounds__(1024) void k_l2(
    const float* __restrict__ z1, const float* __restrict__ zstat,
    const float* __restrict__ g1, const float* __restrict__ b1,
    const float* __restrict__ w2, const float* __restrict__ g2,
    const float* __restrict__ b2, const float* __restrict__ wsc,
    float* __restrict__ part, float* __restrict__ scal) {
  int blk = blockIdx.x;            // s*64 + h
  int s = blk >> 6, h = blk & 63;
  int tid = threadIdx.x, wave = tid >> 6, lane = tid & 63;
  int g32 = lane >> 5, q = lane & 31;    // half-wave group, lane-in-group
  int g = lane >> 4, gl = lane & 15;     // 16-lane view (wsc slice)
  __shared__ float h1_s[N_HID];
  __shared__ float z_s[N_OUT];
  __shared__ float2 red2[32];
  __shared__ float red[16];

  const float* w2base = w2 + (size_t)blk * N_OUT * N_HID;
  int row0 = wave * 16 + g32 * 8;  // this group's first row

  // prefetch round 0: 4 float4 per lane (w2[row0][q*4 + c*128 ..])
  float4 A[4], B[4];
  {
    const float4* rp = (const float4*)(w2base + (size_t)row0 * N_HID) + q;
#pragma unroll
    for (int c = 0; c < 4; ++c) A[c] = rp[c * 32];
  }

  // GN1 over 512 + softplus -> h1_s; mean/var from K1's per-quarter stats.
  float zsum = 0.f, zsq = 0.f;
#pragma unroll
  for (int qq = 0; qq < 4; ++qq) {
    zsum += zstat[(h * 4 + qq) * 2];
    zsq  += zstat[(h * 4 + qq) * 2 + 1];
  }
  float mu1 = zsum * (1.f / N_HID);
  float var1 = zsq * (1.f / N_HID) - mu1 * mu1;
  float r1 = rsqrtf(var1 + EPS_GN);
  if (tid < N_HID) {
    float v1 = z1[h * N_HID + tid];
    float zz = (v1 - mu1) * r1 * g1[h * N_HID + tid] + b1[h * N_HID + tid];
    h1_s[tid] = fmaxf(zz, 0.f) + log1pf(expf(-fabsf(zz)));
  }
  __syncthreads();

  // per-lane h1 fragment: floats q*4 + c*128 ..+3 (o-invariant; loaded once)
  float4 H[4];
#pragma unroll
  for (int c = 0; c < 4; ++c) H[c] = ((const float4*)h1_s)[q + c * 32];

  // main loop: 8 rounds x (2 rows/wave), double-buffered in registers
  float as = 0.f, aq = 0.f;
#pragma unroll
  for (int r = 0; r < 8; ++r) {
    if (r < 7) {
      const float4* rp =
          (const float4*)(w2base + (size_t)(row0 + r + 1) * N_HID) + q;
#pragma unroll
      for (int c = 0; c < 4; ++c) B[c] = rp[c * 32];
    }
    float p = 0.f;
#pragma unroll
    for (int c = 0; c < 4; ++c)
      p += A[c].x * H[c].x + A[c].y * H[c].y + A[c].z * H[c].z + A[c].w * H[c].w;
    p = red32(p);
    if (q == 31) {
      z_s[row0 + r] = p;
      as += p; aq += p * p;
    }
#pragma unroll
    for (int c = 0; c < 4; ++c) A[c] = B[c];
  }
  if (q == 31) red2[wave * 2 + g32] = make_float2(as, aq);

  // fused ws slice: 64 rows o in [s*64,(s+1)*64), one row per 16-lane group
  {
    int o = s * 64 + wave * 4 + g;
    const float4* wr = (const float4*)(wsc + ((size_t)h * N_OUT + o) * N_OUT) + gl;
    float4 v0 = wr[0], v1 = wr[16], v2 = wr[32], v3 = wr[48];
    float p = v0.x + v0.y + v0.z + v0.w + v1.x + v1.y + v1.z + v1.w +
              v2.x + v2.y + v2.z + v2.w + v3.x + v3.y + v3.z + v3.w;
    p = red16(p);
    if (gl == 15) scal[o * N_HEADS + h] = p;
  }
  __syncthreads();

  // GN2 over 256 from the 32 group-partials (LDS broadcast reads)
  float sx = 0.f, sy = 0.f;
#pragma unroll
  for (int i = 0; i < 32; ++i) { sx += red2[i].x; sy += red2[i].y; }
  float mu = sx * (1.f / N_OUT);
  float var = sy * (1.f / N_OUT) - mu * mu;
  float rs = rsqrtf(var + EPS_GN);
  // softmax without max-subtraction: zn is GN-standardized, |zn|<=16 — f32-safe.
  float e = (tid < N_OUT)
                ? expf((z_s[tid] - mu) * rs * g2[(size_t)blk * N_OUT + tid] +
                       b2[(size_t)blk * N_OUT + tid])
                : 0.f;
  float es = block_sum(e, red);
  if (tid < N_OUT) part[(size_t)blk * N_OUT + tid] = e / es;
}

// K3: one block per head. Sums the 4 softmax partials (L2/LLC-hot),
// last_prod (redundant per block, L2-resident), gate logit + sigmoid, finals.
__global__ __launch_bounds__(256) void k_gate_final(
    const float* __restrict__ last, const float* __restrict__ woo,
    const float* __restrict__ part, const float* __restrict__ scal,
    float* __restrict__ out) {
  int h = blockIdx.x;
  int tid = threadIdx.x;
  __shared__ float red[4];

  float osum = 0.f;
#pragma unroll
  for (int ss = 0; ss < 4; ++ss)
    osum += part[(size_t)(ss * 64 + h) * N_OUT + tid];

  // lp[o=tid] = prod_h last[o][h]  (64 contiguous floats per thread)
  const float4* rowL = (const float4*)(last + (size_t)tid * N_HEADS);
  float lp = 1.f;
#pragma unroll
  for (int j = 0; j < 16; ++j) {
    float4 v = rowL[j];
    lp *= v.x * v.y * v.z * v.w;
  }
  float gpart = woo[h * 2 * N_OUT + tid] * lp +
                woo[h * 2 * N_OUT + N_OUT + tid] * osum;
  float logit = block_sum(gpart, red);
  float oo = 1.f / (1.f + expf(-logit));

  float v0 = oo * osum;
  out[tid * N_HEADS + h] = fmaxf(v0, TINY);
  float v1 = v0 * scal[tid * N_HEADS + h];
  out[N_OUT * N_HEADS + tid * N_HEADS + h] = (fabsf(v1) <= TINY) ? TINY : v1;
}

extern "C" void kernel_launch(void* const* d_in, const int* in_sizes, int n_in,
                              void* d_out, int out_size, void* d_ws, size_t ws_size,
                              hipStream_t stream) {
  const float* x    = (const float*)d_in[0];
  const float* last = (const float*)d_in[1];
  const float* qw   = (const float*)d_in[2];
  const float* w1   = (const float*)d_in[3];
  const float* g1   = (const float*)d_in[4];
  const float* b1   = (const float*)d_in[5];
  const float* w2   = (const float*)d_in[6];
  const float* g2   = (const float*)d_in[7];
  const float* b2   = (const float*)d_in[8];
  const float* wsc  = (const float*)d_in[9];
  const float* woo  = (const float*)d_in[10];
  float* out = (float*)d_out;
  float* ws  = (float*)d_ws;

  float* z1    = ws;               // 64*512          = 32768 floats
  float* zstat = ws + 32768;       // 256*2           = 512
  float* part  = ws + 33280;       // 4*64*256        = 65536
  float* scal  = ws + 98816;       // 256*64          = 16384

  hipLaunchKernelGGL(k_z1,        dim3(256), dim3(512),  0, stream,
                     x, qw, w1, z1, zstat);
  hipLaunchKernelGGL(k_l2,        dim3(256), dim3(1024), 0, stream,
                     z1, zstat, g1, b1, w2, g2, b2, wsc, part, scal);
  hipLaunchKernelGGL(k_gate_final,dim3(64),  dim3(256),  0, stream,
                     last, woo, part, scal, out);
}